// Round 23
// baseline (142.437 us; speedup 1.0000x reference)
//
#include <hip/hip_runtime.h>
#include <hip/hip_bf16.h>

#define NN 2048
#define LOG2E 1.4426950408889634f

typedef unsigned int u32;
typedef unsigned short u16;
typedef unsigned char u8;

typedef __attribute__((ext_vector_type(8))) short short8;
typedef __attribute__((ext_vector_type(4))) float f32x4;

__device__ __forceinline__ u16 f2bf(float f){
  __hip_bfloat16 h = __float2bfloat16(f);
  return *reinterpret_cast<u16*>(&h);
}
__device__ __forceinline__ float bf1(u16 u){ return __uint_as_float(((u32)u) << 16); }
__device__ __forceinline__ u32 pack2(float a, float b){
  return (u32)f2bf(a) | ((u32)f2bf(b) << 16);
}
__device__ __forceinline__ void gload16(const void* g, void* l){
  __builtin_amdgcn_global_load_lds((const __attribute__((address_space(1))) u32*)g,
                                   (__attribute__((address_space(3))) u32*)l, 16, 0, 0);
}

// Transpose 4 W f32 [512][512] -> bf16 W^T [n][k]. grid (16,16,4).
__global__ __launch_bounds__(256)
void trw4_k(const float* __restrict__ W0, const float* __restrict__ W1,
            const float* __restrict__ W2, const float* __restrict__ W3,
            u16* __restrict__ WT)
{
  __shared__ float tile[32][33];
  const int zz = blockIdx.z;
  const float* W = (zz == 0) ? W0 : (zz == 1) ? W1 : (zz == 2) ? W2 : W3;
  u16* dst = WT + (size_t)zz * 262144;
  const int t = threadIdx.x;
  const int k0 = blockIdx.x * 32, n0 = blockIdx.y * 32;
  const int c = t & 31, r = t >> 5;
  #pragma unroll
  for (int i = 0; i < 4; ++i)
    tile[r + 8*i][c] = W[(size_t)(k0 + r + 8*i) * 512 + n0 + c];
  __syncthreads();
  #pragma unroll
  for (int i = 0; i < 4; ++i)
    dst[(size_t)(n0 + r + 8*i) * 512 + k0 + c] = f2bf(tile[c][r + 8*i]);
}

// Single-W transpose (fallback path only).
__global__ __launch_bounds__(256)
void trw_k(const float* __restrict__ W, u16* __restrict__ WT)
{
  __shared__ float tile[32][33];
  const int t = threadIdx.x;
  const int k0 = blockIdx.x * 32, n0 = blockIdx.y * 32;
  const int c = t & 31, r = t >> 5;
  #pragma unroll
  for (int i = 0; i < 4; ++i)
    tile[r + 8*i][c] = W[(size_t)(k0 + r + 8*i) * 512 + n0 + c];
  __syncthreads();
  #pragma unroll
  for (int i = 0; i < 4; ++i)
    WT[(size_t)(n0 + r + 8*i) * 512 + k0 + c] = f2bf(tile[c][r + 8*i]);
}

// Double-buffered MFMA GEMM core: C[64 x BN block] = (A @ W^T + bias)*scale.
// SMODE: 1 = scatter bf16 [bh][n][c]; 2 = scatter-TRANSPOSED bf16 [bh][c][n];
//        3 = f32 row-major.
template<int BN, int SMODE, bool ABF16>
__device__ __forceinline__
void gemm_core(const void* __restrict__ Av, const u16* __restrict__ WT,
               const float* __restrict__ bias, void* __restrict__ Cd,
               float scale, int m0, int n0)
{
  constexpr int NI  = BN / 64;
  constexpr int WNL = BN / 32;
  __shared__ u16 As[2][64*64];
  __shared__ u16 Ws[2][BN*64];

  const int t = threadIdx.x;
  const int lane = t & 63;
  const int w = t >> 6;
  const int g = lane >> 4, r15 = lane & 15;
  const int wn = w * (BN/4);

  const int arow = t >> 2, akc = (t & 3) * 16, as0 = (t & 3) * 2;
  const int wrn = (BN==128) ? (t>>1) : (t>>2);
  const int wkc = (BN==128) ? ((t&1)*32) : ((t&3)*16);
  const int wsb = (BN==128) ? ((t&1)*4)  : ((t&3)*2);

  uint4  war[WNL];
  uint4  aab[2];
  float4 aaf[4];

  auto loadA = [&](int k0){
    if constexpr (ABF16) {
      const u16* A = (const u16*)Av;
      aab[0] = *reinterpret_cast<const uint4*>(A + (size_t)(m0+arow)*512 + k0 + akc);
      aab[1] = *reinterpret_cast<const uint4*>(A + (size_t)(m0+arow)*512 + k0 + akc + 8);
    } else {
      const float* A = (const float*)Av;
      #pragma unroll
      for (int q = 0; q < 4; ++q)
        aaf[q] = *reinterpret_cast<const float4*>(A + (size_t)(m0+arow)*512 + k0 + akc + 4*q);
    }
  };
  auto loadW = [&](int k0){
    #pragma unroll
    for (int i = 0; i < WNL; ++i)
      war[i] = *reinterpret_cast<const uint4*>(WT + (size_t)(n0+wrn)*512 + k0 + wkc + 8*i);
  };
  auto writeA = [&](int bf){
    uint4 v0, v1;
    if constexpr (ABF16) { v0 = aab[0]; v1 = aab[1]; }
    else {
      v0.x = pack2(aaf[0].x, aaf[0].y); v0.y = pack2(aaf[0].z, aaf[0].w);
      v0.z = pack2(aaf[1].x, aaf[1].y); v0.w = pack2(aaf[1].z, aaf[1].w);
      v1.x = pack2(aaf[2].x, aaf[2].y); v1.y = pack2(aaf[2].z, aaf[2].w);
      v1.z = pack2(aaf[3].x, aaf[3].y); v1.w = pack2(aaf[3].z, aaf[3].w);
    }
    *reinterpret_cast<uint4*>(&As[bf][arow*64 + (((as0  ) ^ (arow&7)) << 3)]) = v0;
    *reinterpret_cast<uint4*>(&As[bf][arow*64 + (((as0+1) ^ (arow&7)) << 3)]) = v1;
  };
  auto writeW = [&](int bf){
    #pragma unroll
    for (int i = 0; i < WNL; ++i)
      *reinterpret_cast<uint4*>(&Ws[bf][wrn*64 + (((wsb+i) ^ (wrn&7)) << 3)]) = war[i];
  };

  const f32x4 fz = {0.f,0.f,0.f,0.f};
  f32x4 acc[4][NI];
  #pragma unroll
  for (int mi = 0; mi < 4; ++mi)
    #pragma unroll
    for (int ni = 0; ni < NI; ++ni) acc[mi][ni] = fz;

  loadA(0); loadW(0);
  writeA(0); writeW(0);
  __syncthreads();

  for (int kt = 0; kt < 8; ++kt) {
    const int cur = kt & 1;
    if (kt < 7) { loadA((kt+1)*64); loadW((kt+1)*64); }
    #pragma unroll
    for (int ks = 0; ks < 2; ++ks) {
      short8 bfr[NI], afr[4];
      #pragma unroll
      for (int ni = 0; ni < NI; ++ni) {
        const int n = wn + 16*ni + r15;
        bfr[ni] = *reinterpret_cast<const short8*>(&Ws[cur][n*64 + (((ks*4+g) ^ (n&7)) << 3)]);
      }
      #pragma unroll
      for (int mi = 0; mi < 4; ++mi) {
        const int m = 16*mi + r15;
        afr[mi] = *reinterpret_cast<const short8*>(&As[cur][m*64 + (((ks*4+g) ^ (m&7)) << 3)]);
      }
      #pragma unroll
      for (int mi = 0; mi < 4; ++mi)
        #pragma unroll
        for (int ni = 0; ni < NI; ++ni)
          acc[mi][ni] = __builtin_amdgcn_mfma_f32_16x16x32_bf16(afr[mi], bfr[ni], acc[mi][ni], 0, 0, 0);
    }
    if (kt < 7) { writeA(cur^1); writeW(cur^1); }
    __syncthreads();
  }

  float bia[NI];
  #pragma unroll
  for (int ni = 0; ni < NI; ++ni) bia[ni] = bias[n0 + wn + 16*ni + r15];
  #pragma unroll
  for (int mi = 0; mi < 4; ++mi) {
    #pragma unroll
    for (int ni = 0; ni < NI; ++ni) {
      #pragma unroll
      for (int j = 0; j < 4; ++j) {
        const int row = m0 + 16*mi + 4*g + j;
        const int col = n0 + wn + 16*ni + r15;
        const float v = (acc[mi][ni][j] + bia[ni]) * scale;
        if constexpr (SMODE == 1) {
          const int bb = row & 1, ntok = row >> 1;
          const int hh = col >> 6, c = col & 63;
          ((u16*)Cd)[(((size_t)(bb*8 + hh) * NN + ntok) * 64) + c] = f2bf(v);
        } else if constexpr (SMODE == 2) {
          const int bb = row & 1, ntok = row >> 1;
          const int hh = col >> 6, c = col & 63;
          ((u16*)Cd)[(((size_t)(bb*8 + hh) * 64 + c) * NN) + ntok] = f2bf(v);
        } else {
          ((float*)Cd)[(size_t)row * 512 + col] = v;
        }
      }
    }
  }
}

// Merged front kernel: blocks [0,768) run QKV GEMM tiles (compute-bound; V tile
// writes TRANSPOSED VT[bh][c][n]), blocks [768, 768+8192) run mask prep
// (HBM-bound). Independent roles; co-residency overlaps HBM with MFMA.
__global__ __launch_bounds__(256)
void front_k(const float* __restrict__ x0, const float* __restrict__ x1,
             const float* __restrict__ x2, const u16* __restrict__ WT3,
             const float* __restrict__ b0, const float* __restrict__ b1,
             const float* __restrict__ b2, u16* __restrict__ dst,
             u16* __restrict__ VT, float qscale,
             const int* __restrict__ am, const int* __restrict__ kp,
             u8* __restrict__ cmb)
{
  const int bid = blockIdx.x;
  if (bid < 768) {
    const int z  = bid >> 8;
    const int rem = bid & 255;
    const int bx = rem & 63, by = rem >> 6;
    const float* A    = (z == 0) ? x0 : (z == 1) ? x1 : x2;
    const float* bias = (z == 0) ? b0 : (z == 1) ? b1 : b2;
    if (z == 2) {
      gemm_core<128, 2, false>(A, WT3 + 2*262144, bias, VT, 1.0f, bx*64, by*128);
    } else {
      gemm_core<128, 1, false>(A, WT3 + (size_t)z*262144, bias,
                               dst + (size_t)z*2097152,
                               (z == 0) ? qscale : 1.0f, bx*64, by*128);
    }
  } else {
    const size_t tid  = (size_t)(bid - 768) * 256 + threadIdx.x;
    const size_t base = tid * 4;
    const int row = (int)(base >> 11);
    const int m0  = (int)(base & 2047);
    const int b = row >> 11, n = row & 2047;
    const size_t e0 = (((size_t)(b*3) * NN) + n) * NN + m0;
    const int4 a0 = *reinterpret_cast<const int4*>(am + e0);
    const int4 a1 = *reinterpret_cast<const int4*>(am + e0 + (size_t)NN*NN);
    const int4 a2 = *reinterpret_cast<const int4*>(am + e0 + 2*(size_t)NN*NN);
    const int4 kv = *reinterpret_cast<const int4*>(kp + (size_t)b*NN + m0);
    const int a0v[4] = {a0.x,a0.y,a0.z,a0.w};
    const int a1v[4] = {a1.x,a1.y,a1.z,a1.w};
    const int a2v[4] = {a2.x,a2.y,a2.z,a2.w};
    const int kvv[4] = {kv.x,kv.y,kv.z,kv.w};
    uchar4 out;
    u8* o = (u8*)&out;
    #pragma unroll
    for (int i = 0; i < 4; ++i)
      o[i] = (u8)((a0v[i]?1:0) | (a1v[i]?2:0) | (a2v[i]?4:0) | (kvv[i]?8:0));
    *reinterpret_cast<uchar4*>(cmb + base) = out;
  }
}

// Output projection: grid (64, 8).
__global__ __launch_bounds__(256)
void gemm_wo(const u16* __restrict__ Ob, const u16* __restrict__ WT,
             const float* __restrict__ bias, float* __restrict__ out)
{
  gemm_core<64, 3, true>(Ob, WT, bias, out, 1.0f, blockIdx.x*64, blockIdx.y*64);
}

// MFMA flash attention, 8 waves / 128 q, split-K, exp2 domain, 1 barrier/tile.
// BOTH K and V staged via global_load_lds with pre-swizzled sources (V from the
// directly-transposed VT [bh][c][n]); P through per-wave Ps LDS; defer-max;
// bf16 split-K partials; setprio around MFMA clusters. Q pre-scaled 0.125*log2e.
__global__ __launch_bounds__(512)
void attn_mfma(const u16* __restrict__ Q, const u16* __restrict__ K,
               const u16* __restrict__ VT, const u8* __restrict__ cmb,
               const float* __restrict__ mw, u16* __restrict__ O,
               u16* __restrict__ Opart, float2* __restrict__ Ml, int kspan)
{
  __shared__ u16 Ks[2][64*64];  // [key][ch] pre-swizzled (slot^(key&7) at source)
  __shared__ u16 Vs[2][64*64];  // [ch][key], slot = x^(c&7)^(c>>3) (at source)
  __shared__ u16 Ps[8][16*64];  // per wave: [q][key], key-slot(8) XOR (q&7)
  __shared__ float lut[16];     // rel-bias (log2 units), -inf for padded

  const int t = threadIdx.x;
  const int lane = t & 63;
  const int w = t >> 6;
  const int g = lane >> 4;
  const int r15 = lane & 15;
  const int bh = blockIdx.y;
  const int z = blockIdx.z;
  const int b = bh >> 3, h = bh & 7;
  const int n0 = blockIdx.x * 128;
  const int nq = n0 + w*16 + r15;
  const int k_beg = z * kspan;
  const float NEGINF = -__builtin_inff();

  if (t < 16) {
    const float mw0 = mw[h*4+0], mw1 = mw[h*4+1], mw2 = mw[h*4+2];
    const float msc = mw[h*4+3];
    const float mxw = fmaxf(mw0, fmaxf(mw1, mw2));
    const float e0 = __expf(mw0-mxw), e1 = __expf(mw1-mxw), e2 = __expf(mw2-mxw);
    const float inv = msc / (e0+e1+e2);
    float v = ((t & 1) ? 0.f : e0*inv) + ((t & 2) ? 0.f : e1*inv)
            + ((t & 4) ? 0.f : e2*inv);
    lut[t] = (t & 8) ? NEGINF : v * LOG2E;
  }

  const u16* qrow = Q + ((size_t)bh*NN + nq)*64;
  const short8 bq0 = *reinterpret_cast<const short8*>(qrow + 8*g);
  const short8 bq1 = *reinterpret_cast<const short8*>(qrow + 32 + 8*g);

  const u8* crow = cmb + ((size_t)(b*NN + nq))*NN;
  const u16* Kbase  = K  + (size_t)bh*NN*64;
  const u16* VTbase = VT + (size_t)bh*64*NN;

  float m_run = NEGINF, l_run = 0.f;
  const f32x4 fz = {0.f, 0.f, 0.f, 0.f};
  f32x4 oacc[4] = {fz, fz, fz, fz};

  const int sm  = t >> 3;                    // K staging key row 0..63
  const int ssl = t & 7;
  const int kcol = (ssl ^ (sm & 7)) * 8;     // pre-swizzled K source column
  const int vc   = t >> 3;                   // V staging channel row 0..63
  const int vcol = ((t & 7) ^ (vc & 7) ^ (vc >> 3)) * 8;  // pre-swizzled V key col

  auto gloadK = [&](int m0, int bf){
    gload16(Kbase + (size_t)(m0 + sm)*64 + kcol, &Ks[bf][t << 3]);
  };
  auto gloadV = [&](int m0, int bf){
    gload16(VTbase + (size_t)vc*NN + m0 + vcol, &Vs[bf][t << 3]);
  };

  const int ntiles = kspan >> 6;
  gloadK(k_beg, 0);
  gloadV(k_beg, 0);
  __syncthreads();   // drains vmcnt; covers lut + buf0

  for (int it = 0; it < ntiles; ++it) {
    const int cur = it & 1;
    const int m0 = k_beg + it * 64;
    const bool more = (it + 1 < ntiles);
    if (more) { gloadK(m0 + 64, cur ^ 1); gloadV(m0 + 64, cur ^ 1); }

    // S^T = K @ Q^T
    float sv[4][4];
    __builtin_amdgcn_s_setprio(1);
    #pragma unroll
    for (int kt = 0; kt < 4; ++kt) {
      const int key = 16*kt + r15;
      const short8 a0 = *reinterpret_cast<const short8*>(&Ks[cur][key*64 + (((g  ) ^ (key&7)) << 3)]);
      const short8 a1 = *reinterpret_cast<const short8*>(&Ks[cur][key*64 + (((g+4) ^ (key&7)) << 3)]);
      f32x4 s = fz;
      s = __builtin_amdgcn_mfma_f32_16x16x32_bf16(a0, bq0, s, 0, 0, 0);
      s = __builtin_amdgcn_mfma_f32_16x16x32_bf16(a1, bq1, s, 0, 0, 0);
      const u32 cw = *reinterpret_cast<const u32*>(crow + m0 + 16*kt + 4*g);
      #pragma unroll
      for (int j = 0; j < 4; ++j)
        sv[kt][j] = s[j] + lut[(cw >> (8*j)) & 0xfu];
    }
    __builtin_amdgcn_s_setprio(0);
    float pmax = NEGINF;
    #pragma unroll
    for (int kt = 0; kt < 4; ++kt)
      #pragma unroll
      for (int j = 0; j < 4; ++j) pmax = fmaxf(pmax, sv[kt][j]);
    float tmax = pmax;
    tmax = fmaxf(tmax, __shfl_xor(tmax, 16));
    tmax = fmaxf(tmax, __shfl_xor(tmax, 32));

    // defer-max: skip rescale when tile max doesn't grow past THR (wave-uniform)
    const bool skip = __all((m_run != NEGINF) && (tmax <= m_run + 10.0f));
    float nm = m_run, sc = 1.0f;
    if (!skip) {
      nm = fmaxf(m_run, tmax);
      if (nm != NEGINF) { sc = exp2f(m_run - nm); m_run = nm; }
      #pragma unroll
      for (int ct = 0; ct < 4; ++ct) oacc[ct] *= sc;
    }

    // P = exp2(S - m), write P^T (bf16) to per-wave Ps
    float psum = 0.f;
    #pragma unroll
    for (int kt = 0; kt < 4; ++kt) {
      float p[4];
      #pragma unroll
      for (int j = 0; j < 4; ++j) {
        p[j] = (nm == NEGINF) ? 0.f : exp2f(sv[kt][j] - nm);
        psum += p[j];
      }
      const int slot = 2*kt + (g >> 1);
      const int off  = 4 * (g & 1);
      *reinterpret_cast<ushort4*>(&Ps[w][r15*64 + ((slot ^ (r15 & 7)) << 3) + off]) =
        make_ushort4(f2bf(p[0]), f2bf(p[1]), f2bf(p[2]), f2bf(p[3]));
    }
    psum += __shfl_xor(psum, 16);
    psum += __shfl_xor(psum, 32);
    l_run = l_run * sc + psum;

    // O^T += V^T @ P^T
    const short8 bp0 = *reinterpret_cast<const short8*>(&Ps[w][r15*64 + (((g  ) ^ (r15 & 7)) << 3)]);
    const short8 bp1 = *reinterpret_cast<const short8*>(&Ps[w][r15*64 + (((g+4) ^ (r15 & 7)) << 3)]);
    __builtin_amdgcn_s_setprio(1);
    #pragma unroll
    for (int ct = 0; ct < 4; ++ct) {
      const int c = 16*ct + r15;
      const short8 av0 = *reinterpret_cast<const short8*>(
        &Vs[cur][c*64 + ((((g  ) ^ (c&7) ^ (c>>3))) << 3)]);
      const short8 av1 = *reinterpret_cast<const short8*>(
        &Vs[cur][c*64 + ((((g+4) ^ (c&7) ^ (c>>3))) << 3)]);
      oacc[ct] = __builtin_amdgcn_mfma_f32_16x16x32_bf16(av0, bp0, oacc[ct], 0, 0, 0);
      oacc[ct] = __builtin_amdgcn_mfma_f32_16x16x32_bf16(av1, bp1, oacc[ct], 0, 0, 0);
    }
    __builtin_amdgcn_s_setprio(0);

    __syncthreads();
  }

  if (Opart) {
    u16* orow = Opart + (((size_t)(z*16 + bh)) * NN + nq) * 64;
    #pragma unroll
    for (int ct = 0; ct < 4; ++ct)
      *reinterpret_cast<ushort4*>(orow + 16*ct + 4*g) =
        make_ushort4(f2bf(oacc[ct][0]), f2bf(oacc[ct][1]),
                     f2bf(oacc[ct][2]), f2bf(oacc[ct][3]));
    if (g == 0)
      Ml[((size_t)(z*16 + bh)) * NN + nq] = make_float2(m_run, l_run);
  } else {
    const float rinv = 1.f / l_run;
    #pragma unroll
    for (int ct = 0; ct < 4; ++ct) {
      u16* dst = O + ((size_t)(nq*2 + b))*512 + h*64 + 16*ct + 4*g;
      *reinterpret_cast<ushort4*>(dst) =
        make_ushort4(f2bf(oacc[ct][0]*rinv), f2bf(oacc[ct][1]*rinv),
                     f2bf(oacc[ct][2]*rinv), f2bf(oacc[ct][3]*rinv));
    }
  }
}

// Merge split-K partials (bf16 partials, log2-domain m). wave = (bh, q).
__global__ __launch_bounds__(256)
void combine_k(const u16* __restrict__ Opart, const float2* __restrict__ Ml,
               u16* __restrict__ Ob, int nsplit)
{
  const int t = threadIdx.x;
  const int lane = t & 63, w = t >> 6;
  const int q = blockIdx.x * 4 + w;
  const int bh = blockIdx.y;
  const int b = bh >> 3, h = bh & 7;

  float M = -__builtin_inff();
  for (int s = 0; s < nsplit; ++s)
    M = fmaxf(M, Ml[((size_t)(s*16 + bh)) * NN + q].x);

  float num = 0.f, den = 0.f;
  for (int s = 0; s < nsplit; ++s) {
    const float2 ml = Ml[((size_t)(s*16 + bh)) * NN + q];
    const float ws = (ml.x == -__builtin_inff()) ? 0.f : exp2f(ml.x - M);
    den += ws * ml.y;
    num += ws * bf1(Opart[(((size_t)(s*16 + bh)) * NN + q) * 64 + lane]);
  }
  const float r = (den > 0.f) ? num / den : 0.f;
  Ob[((size_t)(q*2 + b)) * 512 + h*64 + lane] = f2bf(r);
}

extern "C" void kernel_launch(void* const* d_in, const int* in_sizes, int n_in,
                              void* d_out, int out_size, void* d_ws, size_t ws_size,
                              hipStream_t stream)
{
  const float* xq = (const float*)d_in[0];
  const float* xk = (const float*)d_in[1];
  const float* xv = (const float*)d_in[2];
  const int*   am = (const int*)d_in[3];
  const int*   kp = (const int*)d_in[4];
  const float* Wq = (const float*)d_in[5];
  const float* bq = (const float*)d_in[6];
  const float* Wk = (const float*)d_in[7];
  const float* bk = (const float*)d_in[8];
  const float* Wv = (const float*)d_in[9];
  const float* bv = (const float*)d_in[10];
  const float* Wo = (const float*)d_in[11];
  const float* bo = (const float*)d_in[12];
  const float* mw = (const float*)d_in[13];

  u16* Qb = (u16*)d_ws;                       // [16][2048][64] bf16, 4 MB
  u16* Kb = Qb + (size_t)16*NN*64;            // 4 MB
  u16* VT = Kb + (size_t)16*NN*64;            // [16][64][2048] bf16, 4 MB (transposed V)
  u16* Ob = VT + (size_t)16*64*NN;            // [4096][512] bf16, 4 MB
  u8*  cmb = (u8*)(Ob + (size_t)4096*512);    // [2][2048][2048] bytes, 8 MB
  u8*  R   = cmb + (size_t)2*NN*NN;           // scratch region

  u16* Opart = (u16*)R;                       // split-K bf16 partials (<= 17.75 MB @ 4)
  const size_t base_bytes = (size_t)(R - (u8*)d_ws);
  int nsplit = 1;
  for (int s = 4; s >= 1; s >>= 1) {
    const size_t need = base_bytes + (size_t)s * 16 * NN * (64*2 + 8);
    if (need <= ws_size) { nsplit = s; break; }
  }
  float2* Ml = (float2*)(Opart + (size_t)nsplit * 16 * NN * 64);
  const bool split = (base_bytes + (size_t)16*NN*(64*2+8) <= ws_size);

  u16* WT4 = (u16*)(R + (size_t)18*1024*1024);
  const bool wt4_ok = (base_bytes + (size_t)18*1024*1024 + 4*262144*2 <= ws_size);
  u16* WT3 = wt4_ok ? WT4 : (u16*)R;
  u16* WTo = wt4_ok ? (WT4 + 3*262144) : Qb;

  const float qscale = 0.125f * LOG2E;
  trw4_k<<<dim3(16, 16, wt4_ok ? 4 : 3), 256, 0, stream>>>(Wq, Wk, Wv, Wo,
                                                           wt4_ok ? WT4 : WT3);
  // merged front: 768 qkv blocks (V written transposed) + 8192 prep blocks
  front_k<<<dim3(768 + 8192), 256, 0, stream>>>(xq, xk, xv, WT3, bq, bk, bv, Qb,
                                                VT, qscale, am, kp, cmb);

  if (split) {
    attn_mfma<<<dim3(16, 16, nsplit), 512, 0, stream>>>(Qb, Kb, VT, cmb, mw, Ob,
                                                        Opart, Ml, NN / nsplit);
    combine_k<<<dim3(NN/4, 16), 256, 0, stream>>>(Opart, Ml, Ob, nsplit);
  } else {
    attn_mfma<<<dim3(16, 16, 1), 512, 0, stream>>>(Qb, Kb, VT, cmb, mw, Ob,
                                                   nullptr, nullptr, NN);
  }
  if (!wt4_ok)
    trw_k<<<dim3(16, 16), 256, 0, stream>>>(Wo, WTo);
  gemm_wo<<<dim3(64, 8), 256, 0, stream>>>(Ob, WTo, bo, (float*)d_out);
}

// Round 24
// 120.900 us; speedup vs baseline: 1.1781x; 1.1781x over previous
//
#include <hip/hip_runtime.h>
#include <hip/hip_bf16.h>

#define NN 2048
#define LOG2E 1.4426950408889634f

typedef unsigned int u32;
typedef unsigned short u16;
typedef unsigned char u8;

typedef __attribute__((ext_vector_type(8))) short short8;
typedef __attribute__((ext_vector_type(4))) float f32x4;

__device__ __forceinline__ u16 f2bf(float f){
  __hip_bfloat16 h = __float2bfloat16(f);
  return *reinterpret_cast<u16*>(&h);
}
__device__ __forceinline__ float bf1(u16 u){ return __uint_as_float(((u32)u) << 16); }
__device__ __forceinline__ u32 pack2(float a, float b){
  return (u32)f2bf(a) | ((u32)f2bf(b) << 16);
}
__device__ __forceinline__ void gload16(const void* g, void* l){
  __builtin_amdgcn_global_load_lds((const __attribute__((address_space(1))) u32*)g,
                                   (__attribute__((address_space(3))) u32*)l, 16, 0, 0);
}

// Transpose 4 W f32 [512][512] -> bf16 W^T [n][k]. grid (16,16,4).
__global__ __launch_bounds__(256)
void trw4_k(const float* __restrict__ W0, const float* __restrict__ W1,
            const float* __restrict__ W2, const float* __restrict__ W3,
            u16* __restrict__ WT)
{
  __shared__ float tile[32][33];
  const int zz = blockIdx.z;
  const float* W = (zz == 0) ? W0 : (zz == 1) ? W1 : (zz == 2) ? W2 : W3;
  u16* dst = WT + (size_t)zz * 262144;
  const int t = threadIdx.x;
  const int k0 = blockIdx.x * 32, n0 = blockIdx.y * 32;
  const int c = t & 31, r = t >> 5;
  #pragma unroll
  for (int i = 0; i < 4; ++i)
    tile[r + 8*i][c] = W[(size_t)(k0 + r + 8*i) * 512 + n0 + c];
  __syncthreads();
  #pragma unroll
  for (int i = 0; i < 4; ++i)
    dst[(size_t)(n0 + r + 8*i) * 512 + k0 + c] = f2bf(tile[c][r + 8*i]);
}

// Single-W transpose (fallback path only).
__global__ __launch_bounds__(256)
void trw_k(const float* __restrict__ W, u16* __restrict__ WT)
{
  __shared__ float tile[32][33];
  const int t = threadIdx.x;
  const int k0 = blockIdx.x * 32, n0 = blockIdx.y * 32;
  const int c = t & 31, r = t >> 5;
  #pragma unroll
  for (int i = 0; i < 4; ++i)
    tile[r + 8*i][c] = W[(size_t)(k0 + r + 8*i) * 512 + n0 + c];
  __syncthreads();
  #pragma unroll
  for (int i = 0; i < 4; ++i)
    WT[(size_t)(n0 + r + 8*i) * 512 + k0 + c] = f2bf(tile[c][r + 8*i]);
}

// Double-buffered MFMA GEMM core. LDS buffers are provided by the CALLER
// (single allocation even if multiple template instantiations coexist).
// SMODE: 1 = scatter bf16 [bh][n][c]; 2 = LDS-staged TRANSPOSED bf16 [bh][c][n]
//        (coalesced 64B runs); 3 = f32 row-major.
template<int BN, int SMODE, bool ABF16>
__device__ __forceinline__
void gemm_core(u16* __restrict__ AsP, u16* __restrict__ WsP,
               const void* __restrict__ Av, const u16* __restrict__ WT,
               const float* __restrict__ bias, void* __restrict__ Cd,
               float scale, int m0, int n0)
{
  constexpr int NI  = BN / 64;
  constexpr int WNL = BN / 32;

  const int t = threadIdx.x;
  const int lane = t & 63;
  const int w = t >> 6;
  const int g = lane >> 4, r15 = lane & 15;
  const int wn = w * (BN/4);

  const int arow = t >> 2, akc = (t & 3) * 16, as0 = (t & 3) * 2;
  const int wrn = (BN==128) ? (t>>1) : (t>>2);
  const int wkc = (BN==128) ? ((t&1)*32) : ((t&3)*16);
  const int wsb = (BN==128) ? ((t&1)*4)  : ((t&3)*2);

  uint4  war[WNL];
  uint4  aab[2];
  float4 aaf[4];

  auto loadA = [&](int k0){
    if constexpr (ABF16) {
      const u16* A = (const u16*)Av;
      aab[0] = *reinterpret_cast<const uint4*>(A + (size_t)(m0+arow)*512 + k0 + akc);
      aab[1] = *reinterpret_cast<const uint4*>(A + (size_t)(m0+arow)*512 + k0 + akc + 8);
    } else {
      const float* A = (const float*)Av;
      #pragma unroll
      for (int q = 0; q < 4; ++q)
        aaf[q] = *reinterpret_cast<const float4*>(A + (size_t)(m0+arow)*512 + k0 + akc + 4*q);
    }
  };
  auto loadW = [&](int k0){
    #pragma unroll
    for (int i = 0; i < WNL; ++i)
      war[i] = *reinterpret_cast<const uint4*>(WT + (size_t)(n0+wrn)*512 + k0 + wkc + 8*i);
  };
  auto writeA = [&](int bf){
    uint4 v0, v1;
    if constexpr (ABF16) { v0 = aab[0]; v1 = aab[1]; }
    else {
      v0.x = pack2(aaf[0].x, aaf[0].y); v0.y = pack2(aaf[0].z, aaf[0].w);
      v0.z = pack2(aaf[1].x, aaf[1].y); v0.w = pack2(aaf[1].z, aaf[1].w);
      v1.x = pack2(aaf[2].x, aaf[2].y); v1.y = pack2(aaf[2].z, aaf[2].w);
      v1.z = pack2(aaf[3].x, aaf[3].y); v1.w = pack2(aaf[3].z, aaf[3].w);
    }
    *reinterpret_cast<uint4*>(&AsP[bf*4096 + arow*64 + (((as0  ) ^ (arow&7)) << 3)]) = v0;
    *reinterpret_cast<uint4*>(&AsP[bf*4096 + arow*64 + (((as0+1) ^ (arow&7)) << 3)]) = v1;
  };
  auto writeW = [&](int bf){
    #pragma unroll
    for (int i = 0; i < WNL; ++i)
      *reinterpret_cast<uint4*>(&WsP[bf*BN*64 + wrn*64 + (((wsb+i) ^ (wrn&7)) << 3)]) = war[i];
  };

  const f32x4 fz = {0.f,0.f,0.f,0.f};
  f32x4 acc[4][NI];
  #pragma unroll
  for (int mi = 0; mi < 4; ++mi)
    #pragma unroll
    for (int ni = 0; ni < NI; ++ni) acc[mi][ni] = fz;

  loadA(0); loadW(0);
  writeA(0); writeW(0);
  __syncthreads();

  for (int kt = 0; kt < 8; ++kt) {
    const int cur = kt & 1;
    if (kt < 7) { loadA((kt+1)*64); loadW((kt+1)*64); }
    #pragma unroll
    for (int ks = 0; ks < 2; ++ks) {
      short8 bfr[NI], afr[4];
      #pragma unroll
      for (int ni = 0; ni < NI; ++ni) {
        const int n = wn + 16*ni + r15;
        bfr[ni] = *reinterpret_cast<const short8*>(&WsP[cur*BN*64 + n*64 + (((ks*4+g) ^ (n&7)) << 3)]);
      }
      #pragma unroll
      for (int mi = 0; mi < 4; ++mi) {
        const int m = 16*mi + r15;
        afr[mi] = *reinterpret_cast<const short8*>(&AsP[cur*4096 + m*64 + (((ks*4+g) ^ (m&7)) << 3)]);
      }
      #pragma unroll
      for (int mi = 0; mi < 4; ++mi)
        #pragma unroll
        for (int ni = 0; ni < NI; ++ni)
          acc[mi][ni] = __builtin_amdgcn_mfma_f32_16x16x32_bf16(afr[mi], bfr[ni], acc[mi][ni], 0, 0, 0);
    }
    if (kt < 7) { writeA(cur^1); writeW(cur^1); }
    __syncthreads();
  }

  float bia[NI];
  #pragma unroll
  for (int ni = 0; ni < NI; ++ni) bia[ni] = bias[n0 + wn + 16*ni + r15];

  if constexpr (SMODE == 2) {
    // Stage transposed tile in LDS (As is dead), then coalesced 64B-run writes.
    u16* Ts = AsP;   // 8192 u16 = exactly the 64x128 tile
    #pragma unroll
    for (int mi = 0; mi < 4; ++mi)
      #pragma unroll
      for (int ni = 0; ni < NI; ++ni)
        #pragma unroll
        for (int j = 0; j < 4; ++j) {
          const int lr = 16*mi + 4*g + j;            // local row (token*2+b)
          const int cl = wn + 16*ni + r15;           // local col (2 heads x 64)
          const float v = (acc[mi][ni][j] + bia[ni]) * scale;
          Ts[cl*64 + (lr ^ ((cl & 7) << 3))] = f2bf(v);
        }
    __syncthreads();
    const int bb = t >> 7, rem = t & 127;
    const int hl = rem >> 6, c = rem & 63;
    const int cl = hl*64 + c;
    const int mask = (cl & 7) << 3;
    const int tok0 = m0 >> 1;
    const int hh = (n0 >> 6) + hl;
    u32 ow[16];
    #pragma unroll
    for (int i = 0; i < 16; ++i) {
      const u16 lo = Ts[cl*64 + ((4*i     + bb) ^ mask)];
      const u16 hi = Ts[cl*64 + ((4*i + 2 + bb) ^ mask)];
      ow[i] = (u32)lo | ((u32)hi << 16);
    }
    u16* dst = (u16*)Cd + (((size_t)(bb*8 + hh) * 64 + c) * NN) + tok0;
    *reinterpret_cast<uint4*>(dst)      = make_uint4(ow[0], ow[1], ow[2], ow[3]);
    *reinterpret_cast<uint4*>(dst + 8)  = make_uint4(ow[4], ow[5], ow[6], ow[7]);
    *reinterpret_cast<uint4*>(dst + 16) = make_uint4(ow[8], ow[9], ow[10], ow[11]);
    *reinterpret_cast<uint4*>(dst + 24) = make_uint4(ow[12], ow[13], ow[14], ow[15]);
  } else {
    #pragma unroll
    for (int mi = 0; mi < 4; ++mi) {
      #pragma unroll
      for (int ni = 0; ni < NI; ++ni) {
        #pragma unroll
        for (int j = 0; j < 4; ++j) {
          const int row = m0 + 16*mi + 4*g + j;
          const int col = n0 + wn + 16*ni + r15;
          const float v = (acc[mi][ni][j] + bia[ni]) * scale;
          if constexpr (SMODE == 1) {
            const int bb = row & 1, ntok = row >> 1;
            const int hh = col >> 6, c = col & 63;
            ((u16*)Cd)[(((size_t)(bb*8 + hh) * NN + ntok) * 64) + c] = f2bf(v);
          } else {
            ((float*)Cd)[(size_t)row * 512 + col] = v;
          }
        }
      }
    }
  }
}

// Merged front kernel: blocks [0,768) run QKV GEMM tiles (V tile writes
// transposed VT via LDS-staged coalesced runs), blocks [768,768+8192) run mask
// prep. Shared LDS declared ONCE here (single 48KB allocation).
__global__ __launch_bounds__(256)
void front_k(const float* __restrict__ x0, const float* __restrict__ x1,
             const float* __restrict__ x2, const u16* __restrict__ WT3,
             const float* __restrict__ b0, const float* __restrict__ b1,
             const float* __restrict__ b2, u16* __restrict__ dst,
             u16* __restrict__ VT, float qscale,
             const int* __restrict__ am, const int* __restrict__ kp,
             u8* __restrict__ cmb)
{
  __shared__ u16 shAs[2*64*64];
  __shared__ u16 shWs[2*128*64];
  const int bid = blockIdx.x;
  if (bid < 768) {
    const int z  = bid >> 8;
    const int rem = bid & 255;
    const int bx = rem & 63, by = rem >> 6;
    const float* A    = (z == 0) ? x0 : (z == 1) ? x1 : x2;
    const float* bias = (z == 0) ? b0 : (z == 1) ? b1 : b2;
    if (z == 2) {
      gemm_core<128, 2, false>(shAs, shWs, A, WT3 + 2*262144, bias, VT, 1.0f,
                               bx*64, by*128);
    } else {
      gemm_core<128, 1, false>(shAs, shWs, A, WT3 + (size_t)z*262144, bias,
                               dst + (size_t)z*2097152,
                               (z == 0) ? qscale : 1.0f, bx*64, by*128);
    }
  } else {
    const size_t tid  = (size_t)(bid - 768) * 256 + threadIdx.x;
    const size_t base = tid * 4;
    const int row = (int)(base >> 11);
    const int m0  = (int)(base & 2047);
    const int b = row >> 11, n = row & 2047;
    const size_t e0 = (((size_t)(b*3) * NN) + n) * NN + m0;
    const int4 a0 = *reinterpret_cast<const int4*>(am + e0);
    const int4 a1 = *reinterpret_cast<const int4*>(am + e0 + (size_t)NN*NN);
    const int4 a2 = *reinterpret_cast<const int4*>(am + e0 + 2*(size_t)NN*NN);
    const int4 kv = *reinterpret_cast<const int4*>(kp + (size_t)b*NN + m0);
    const int a0v[4] = {a0.x,a0.y,a0.z,a0.w};
    const int a1v[4] = {a1.x,a1.y,a1.z,a1.w};
    const int a2v[4] = {a2.x,a2.y,a2.z,a2.w};
    const int kvv[4] = {kv.x,kv.y,kv.z,kv.w};
    uchar4 out;
    u8* o = (u8*)&out;
    #pragma unroll
    for (int i = 0; i < 4; ++i)
      o[i] = (u8)((a0v[i]?1:0) | (a1v[i]?2:0) | (a2v[i]?4:0) | (kvv[i]?8:0));
    *reinterpret_cast<uchar4*>(cmb + base) = out;
  }
}

// Output projection: grid (64, 8).
__global__ __launch_bounds__(256)
void gemm_wo(const u16* __restrict__ Ob, const u16* __restrict__ WT,
             const float* __restrict__ bias, float* __restrict__ out)
{
  __shared__ u16 shAs[2*64*64];
  __shared__ u16 shWs[2*64*64];
  gemm_core<64, 3, true>(shAs, shWs, Ob, WT, bias, out, 1.0f,
                         blockIdx.x*64, blockIdx.y*64);
}

// MFMA flash attention (round-22 verified): 8 waves / 128 q, split-K, exp2
// domain, 1 barrier/tile, K and V both via global_load_lds with pre-swizzled
// sources (V from VT [bh][c][n]); Ps-LDS P path; defer-max; bf16 partials;
// setprio around MFMA clusters. Q pre-scaled 0.125*log2e.
__global__ __launch_bounds__(512)
void attn_mfma(const u16* __restrict__ Q, const u16* __restrict__ K,
               const u16* __restrict__ VT, const u8* __restrict__ cmb,
               const float* __restrict__ mw, u16* __restrict__ O,
               u16* __restrict__ Opart, float2* __restrict__ Ml, int kspan)
{
  __shared__ u16 Ks[2][64*64];
  __shared__ u16 Vs[2][64*64];
  __shared__ u16 Ps[8][16*64];
  __shared__ float lut[16];

  const int t = threadIdx.x;
  const int lane = t & 63;
  const int w = t >> 6;
  const int g = lane >> 4;
  const int r15 = lane & 15;
  const int bh = blockIdx.y;
  const int z = blockIdx.z;
  const int b = bh >> 3, h = bh & 7;
  const int n0 = blockIdx.x * 128;
  const int nq = n0 + w*16 + r15;
  const int k_beg = z * kspan;
  const float NEGINF = -__builtin_inff();

  if (t < 16) {
    const float mw0 = mw[h*4+0], mw1 = mw[h*4+1], mw2 = mw[h*4+2];
    const float msc = mw[h*4+3];
    const float mxw = fmaxf(mw0, fmaxf(mw1, mw2));
    const float e0 = __expf(mw0-mxw), e1 = __expf(mw1-mxw), e2 = __expf(mw2-mxw);
    const float inv = msc / (e0+e1+e2);
    float v = ((t & 1) ? 0.f : e0*inv) + ((t & 2) ? 0.f : e1*inv)
            + ((t & 4) ? 0.f : e2*inv);
    lut[t] = (t & 8) ? NEGINF : v * LOG2E;
  }

  const u16* qrow = Q + ((size_t)bh*NN + nq)*64;
  const short8 bq0 = *reinterpret_cast<const short8*>(qrow + 8*g);
  const short8 bq1 = *reinterpret_cast<const short8*>(qrow + 32 + 8*g);

  const u8* crow = cmb + ((size_t)(b*NN + nq))*NN;
  const u16* Kbase  = K  + (size_t)bh*NN*64;
  const u16* VTbase = VT + (size_t)bh*64*NN;

  float m_run = NEGINF, l_run = 0.f;
  const f32x4 fz = {0.f, 0.f, 0.f, 0.f};
  f32x4 oacc[4] = {fz, fz, fz, fz};

  const int sm  = t >> 3;
  const int ssl = t & 7;
  const int kcol = (ssl ^ (sm & 7)) * 8;
  const int vc   = t >> 3;
  const int vcol = ((t & 7) ^ (vc & 7) ^ (vc >> 3)) * 8;

  auto gloadK = [&](int m0, int bf){
    gload16(Kbase + (size_t)(m0 + sm)*64 + kcol, &Ks[bf][t << 3]);
  };
  auto gloadV = [&](int m0, int bf){
    gload16(VTbase + (size_t)vc*NN + m0 + vcol, &Vs[bf][t << 3]);
  };

  const int ntiles = kspan >> 6;
  gloadK(k_beg, 0);
  gloadV(k_beg, 0);
  __syncthreads();

  for (int it = 0; it < ntiles; ++it) {
    const int cur = it & 1;
    const int m0 = k_beg + it * 64;
    const bool more = (it + 1 < ntiles);
    if (more) { gloadK(m0 + 64, cur ^ 1); gloadV(m0 + 64, cur ^ 1); }

    float sv[4][4];
    __builtin_amdgcn_s_setprio(1);
    #pragma unroll
    for (int kt = 0; kt < 4; ++kt) {
      const int key = 16*kt + r15;
      const short8 a0 = *reinterpret_cast<const short8*>(&Ks[cur][key*64 + (((g  ) ^ (key&7)) << 3)]);
      const short8 a1 = *reinterpret_cast<const short8*>(&Ks[cur][key*64 + (((g+4) ^ (key&7)) << 3)]);
      f32x4 s = fz;
      s = __builtin_amdgcn_mfma_f32_16x16x32_bf16(a0, bq0, s, 0, 0, 0);
      s = __builtin_amdgcn_mfma_f32_16x16x32_bf16(a1, bq1, s, 0, 0, 0);
      const u32 cw = *reinterpret_cast<const u32*>(crow + m0 + 16*kt + 4*g);
      #pragma unroll
      for (int j = 0; j < 4; ++j)
        sv[kt][j] = s[j] + lut[(cw >> (8*j)) & 0xfu];
    }
    __builtin_amdgcn_s_setprio(0);
    float pmax = NEGINF;
    #pragma unroll
    for (int kt = 0; kt < 4; ++kt)
      #pragma unroll
      for (int j = 0; j < 4; ++j) pmax = fmaxf(pmax, sv[kt][j]);
    float tmax = pmax;
    tmax = fmaxf(tmax, __shfl_xor(tmax, 16));
    tmax = fmaxf(tmax, __shfl_xor(tmax, 32));

    const bool skip = __all((m_run != NEGINF) && (tmax <= m_run + 10.0f));
    float nm = m_run, sc = 1.0f;
    if (!skip) {
      nm = fmaxf(m_run, tmax);
      if (nm != NEGINF) { sc = exp2f(m_run - nm); m_run = nm; }
      #pragma unroll
      for (int ct = 0; ct < 4; ++ct) oacc[ct] *= sc;
    }

    float psum = 0.f;
    #pragma unroll
    for (int kt = 0; kt < 4; ++kt) {
      float p[4];
      #pragma unroll
      for (int j = 0; j < 4; ++j) {
        p[j] = (nm == NEGINF) ? 0.f : exp2f(sv[kt][j] - nm);
        psum += p[j];
      }
      const int slot = 2*kt + (g >> 1);
      const int off  = 4 * (g & 1);
      *reinterpret_cast<ushort4*>(&Ps[w][r15*64 + ((slot ^ (r15 & 7)) << 3) + off]) =
        make_ushort4(f2bf(p[0]), f2bf(p[1]), f2bf(p[2]), f2bf(p[3]));
    }
    psum += __shfl_xor(psum, 16);
    psum += __shfl_xor(psum, 32);
    l_run = l_run * sc + psum;

    const short8 bp0 = *reinterpret_cast<const short8*>(&Ps[w][r15*64 + (((g  ) ^ (r15 & 7)) << 3)]);
    const short8 bp1 = *reinterpret_cast<const short8*>(&Ps[w][r15*64 + (((g+4) ^ (r15 & 7)) << 3)]);
    __builtin_amdgcn_s_setprio(1);
    #pragma unroll
    for (int ct = 0; ct < 4; ++ct) {
      const int c = 16*ct + r15;
      const short8 av0 = *reinterpret_cast<const short8*>(
        &Vs[cur][c*64 + ((((g  ) ^ (c&7) ^ (c>>3))) << 3)]);
      const short8 av1 = *reinterpret_cast<const short8*>(
        &Vs[cur][c*64 + ((((g+4) ^ (c&7) ^ (c>>3))) << 3)]);
      oacc[ct] = __builtin_amdgcn_mfma_f32_16x16x32_bf16(av0, bp0, oacc[ct], 0, 0, 0);
      oacc[ct] = __builtin_amdgcn_mfma_f32_16x16x32_bf16(av1, bp1, oacc[ct], 0, 0, 0);
    }
    __builtin_amdgcn_s_setprio(0);

    __syncthreads();
  }

  if (Opart) {
    u16* orow = Opart + (((size_t)(z*16 + bh)) * NN + nq) * 64;
    #pragma unroll
    for (int ct = 0; ct < 4; ++ct)
      *reinterpret_cast<ushort4*>(orow + 16*ct + 4*g) =
        make_ushort4(f2bf(oacc[ct][0]), f2bf(oacc[ct][1]),
                     f2bf(oacc[ct][2]), f2bf(oacc[ct][3]));
    if (g == 0)
      Ml[((size_t)(z*16 + bh)) * NN + nq] = make_float2(m_run, l_run);
  } else {
    const float rinv = 1.f / l_run;
    #pragma unroll
    for (int ct = 0; ct < 4; ++ct) {
      u16* dst = O + ((size_t)(nq*2 + b))*512 + h*64 + 16*ct + 4*g;
      *reinterpret_cast<ushort4*>(dst) =
        make_ushort4(f2bf(oacc[ct][0]*rinv), f2bf(oacc[ct][1]*rinv),
                     f2bf(oacc[ct][2]*rinv), f2bf(oacc[ct][3]*rinv));
    }
  }
}

// Merge split-K partials (bf16 partials, log2-domain m). wave = (bh, q).
__global__ __launch_bounds__(256)
void combine_k(const u16* __restrict__ Opart, const float2* __restrict__ Ml,
               u16* __restrict__ Ob, int nsplit)
{
  const int t = threadIdx.x;
  const int lane = t & 63, w = t >> 6;
  const int q = blockIdx.x * 4 + w;
  const int bh = blockIdx.y;
  const int b = bh >> 3, h = bh & 7;

  float M = -__builtin_inff();
  for (int s = 0; s < nsplit; ++s)
    M = fmaxf(M, Ml[((size_t)(s*16 + bh)) * NN + q].x);

  float num = 0.f, den = 0.f;
  for (int s = 0; s < nsplit; ++s) {
    const float2 ml = Ml[((size_t)(s*16 + bh)) * NN + q];
    const float ws = (ml.x == -__builtin_inff()) ? 0.f : exp2f(ml.x - M);
    den += ws * ml.y;
    num += ws * bf1(Opart[(((size_t)(s*16 + bh)) * NN + q) * 64 + lane]);
  }
  const float r = (den > 0.f) ? num / den : 0.f;
  Ob[((size_t)(q*2 + b)) * 512 + h*64 + lane] = f2bf(r);
}

extern "C" void kernel_launch(void* const* d_in, const int* in_sizes, int n_in,
                              void* d_out, int out_size, void* d_ws, size_t ws_size,
                              hipStream_t stream)
{
  const float* xq = (const float*)d_in[0];
  const float* xk = (const float*)d_in[1];
  const float* xv = (const float*)d_in[2];
  const int*   am = (const int*)d_in[3];
  const int*   kp = (const int*)d_in[4];
  const float* Wq = (const float*)d_in[5];
  const float* bq = (const float*)d_in[6];
  const float* Wk = (const float*)d_in[7];
  const float* bk = (const float*)d_in[8];
  const float* Wv = (const float*)d_in[9];
  const float* bv = (const float*)d_in[10];
  const float* Wo = (const float*)d_in[11];
  const float* bo = (const float*)d_in[12];
  const float* mw = (const float*)d_in[13];

  u16* Qb = (u16*)d_ws;                       // [16][2048][64] bf16, 4 MB
  u16* Kb = Qb + (size_t)16*NN*64;            // 4 MB
  u16* VT = Kb + (size_t)16*NN*64;            // [16][64][2048] bf16, 4 MB (transposed V)
  u16* Ob = VT + (size_t)16*64*NN;            // [4096][512] bf16, 4 MB
  u8*  cmb = (u8*)(Ob + (size_t)4096*512);    // [2][2048][2048] bytes, 8 MB
  u8*  R   = cmb + (size_t)2*NN*NN;           // scratch region

  u16* Opart = (u16*)R;                       // split-K bf16 partials (<= 17.75 MB @ 4)
  const size_t base_bytes = (size_t)(R - (u8*)d_ws);
  int nsplit = 1;
  for (int s = 4; s >= 1; s >>= 1) {
    const size_t need = base_bytes + (size_t)s * 16 * NN * (64*2 + 8);
    if (need <= ws_size) { nsplit = s; break; }
  }
  float2* Ml = (float2*)(Opart + (size_t)nsplit * 16 * NN * 64);
  const bool split = (base_bytes + (size_t)16*NN*(64*2+8) <= ws_size);

  u16* WT4 = (u16*)(R + (size_t)18*1024*1024);
  const bool wt4_ok = (base_bytes + (size_t)18*1024*1024 + 4*262144*2 <= ws_size);
  u16* WT3 = wt4_ok ? WT4 : (u16*)R;
  u16* WTo = wt4_ok ? (WT4 + 3*262144) : Qb;

  const float qscale = 0.125f * LOG2E;
  trw4_k<<<dim3(16, 16, wt4_ok ? 4 : 3), 256, 0, stream>>>(Wq, Wk, Wv, Wo,
                                                           wt4_ok ? WT4 : WT3);
  // merged front: 768 qkv blocks (V written transposed via LDS staging)
  // + 8192 prep blocks
  front_k<<<dim3(768 + 8192), 256, 0, stream>>>(xq, xk, xv, WT3, bq, bk, bv, Qb,
                                                VT, qscale, am, kp, cmb);

  if (split) {
    attn_mfma<<<dim3(16, 16, nsplit), 512, 0, stream>>>(Qb, Kb, VT, cmb, mw, Ob,
                                                        Opart, Ml, NN / nsplit);
    combine_k<<<dim3(NN/4, 16), 256, 0, stream>>>(Opart, Ml, Ob, nsplit);
  } else {
    attn_mfma<<<dim3(16, 16, 1), 512, 0, stream>>>(Qb, Kb, VT, cmb, mw, Ob,
                                                   nullptr, nullptr, NN);
  }
  if (!wt4_ok)
    trw_k<<<dim3(16, 16), 256, 0, stream>>>(Wo, WTo);
  gemm_wo<<<dim3(64, 8), 256, 0, stream>>>(Ob, WTo, bo, (float*)d_out);
}